// Round 12
// baseline (250.426 us; speedup 1.0000x reference)
//
#include <hip/hip_runtime.h>
#include <math.h>

#define HID 128
#define NHEAD 8
#define NL 3
#define NS 256
#define ROWS 4096

typedef __attribute__((ext_vector_type(8))) short bf16x8;
typedef __attribute__((ext_vector_type(4))) float f32x4;

__device__ __forceinline__ float us2f(unsigned short s) { return __uint_as_float(((unsigned)s) << 16); }
__device__ __forceinline__ unsigned short f2b(float f) {   // RNE fp32->bf16
    unsigned u = __float_as_uint(f);
    return (unsigned short)((u + 0x7fff + ((u >> 16) & 1)) >> 16);
}

// ---------- prep: weight split+transpose to bf16 hi/lo planes [N][K] + edge scalars
// blocks: [0,144) Wh, [144,336) W1, [336,528) W2, 528 edge scalars.
__global__ __launch_bounds__(256) void k_prep(
    const float* __restrict__ Wh, const float* __restrict__ W1, const float* __restrict__ W2,
    const float* __restrict__ We_in, const float* __restrict__ We,
    unsigned short* __restrict__ WhH, unsigned short* __restrict__ WhL,
    unsigned short* __restrict__ W1H, unsigned short* __restrict__ W1L,
    unsigned short* __restrict__ W2H, unsigned short* __restrict__ W2L,
    float* __restrict__ sbuf)
{
    int b = blockIdx.x, t = threadIdx.x;
    if (b == 528) {                       // edge scalars (rank-1 collapse of e @ We)
        if (t < NL * 2 * NHEAD) {
            int l = t / (2 * NHEAD), j = t % (2 * NHEAD);
            float acc = 0.f;
            for (int c = 0; c < HID; ++c)
                acc += We_in[c] * We[(long)(l * HID + c) * (2 * NHEAD) + j];
            sbuf[t] = acc;
        }
        return;
    }
    const float* S; unsigned short *OH, *OL; int K, N, kt, nt;
    if (b < 144) {
        int l = b / 48, rem = b % 48; kt = rem & 3; nt = rem >> 2; K = 128; N = 384;
        S = Wh + (long)l * 128 * 384; OH = WhH + (long)l * 384 * 128; OL = WhL + (long)l * 384 * 128;
    } else if (b < 336) {
        int b2 = b - 144; int l = b2 / 64, rem = b2 % 64; kt = rem & 3; nt = rem >> 2; K = 128; N = 512;
        S = W1 + (long)l * 128 * 512; OH = W1H + (long)l * 512 * 128; OL = W1L + (long)l * 512 * 128;
    } else {
        int b2 = b - 336; int l = b2 / 64, rem = b2 % 64; kt = rem & 15; nt = rem >> 4; K = 512; N = 128;
        S = W2 + (long)l * 512 * 128; OH = W2H + (long)l * 128 * 512; OL = W2L + (long)l * 128 * 512;
    }
    __shared__ float sm[32][33];
    int i0 = t >> 5, j = t & 31;
#pragma unroll
    for (int p = 0; p < 4; ++p) {
        int i = i0 + p * 8;
        sm[i][j] = S[(long)(kt * 32 + i) * N + nt * 32 + j];
    }
    __syncthreads();
#pragma unroll
    for (int p = 0; p < 4; ++p) {
        int n = i0 + p * 8;
        float v = sm[j][n];
        unsigned short hh = f2b(v);
        long o = (long)(nt * 32 + n) * K + kt * 32 + j;
        OH[o] = hh; OL[o] = f2b(v - us2f(hh));
    }
}

// ---------- fused LN + split-bf16 MFMA GEMM, K=128 single-shot, 64x64 tile, 4 waves.
// embed mode (nf != null): LN input is nf@Wn computed in-register; col-block 0 writes h.
// mode 0: Cf = acc     mode 1: relu -> Ch/Cl planes
__global__ __launch_bounds__(256) void k_fgemm(
    const float* __restrict__ x, const float* __restrict__ x2,
    const float* __restrict__ nf, const float* __restrict__ Wn, float* __restrict__ hout,
    const float* __restrict__ g, const float* __restrict__ b,
    const unsigned short* __restrict__ WH, const unsigned short* __restrict__ WL,
    float* __restrict__ Cf, unsigned short* __restrict__ Ch, unsigned short* __restrict__ Cl,
    int Nc, int mode)
{
    __shared__ unsigned short sAh[64 * 136], sAl[64 * 136];   // [m][k]
    __shared__ unsigned short sWh[64 * 136], sWl[64 * 136];   // [n][k]
    int t = threadIdx.x;
    int row0 = blockIdx.y * 64, col0 = blockIdx.x * 64;

    // ---- prefetch W planes into regs (latency hidden by LN section below)
    uint4 wreg[8];
    {
        int rr0 = t >> 4, ck = t & 15;
#pragma unroll
        for (int p = 0; p < 4; ++p) {
            wreg[p]     = *(const uint4*)&WH[(long)(col0 + rr0 + p * 16) * 128 + ck * 8];
            wreg[4 + p] = *(const uint4*)&WL[(long)(col0 + rr0 + p * 16) * 128 + ck * 8];
        }
    }
    // ---- LN of 64 A-rows: 2 passes x 32 rows, 8 threads/row, 16 cols each
#pragma unroll
    for (int pass = 0; pass < 2; ++pass) {
        int row = pass * 32 + (t >> 3);
        int p = t & 7, cb = p * 16;
        float v[16];
        if (nf) {
            float n0 = nf[2 * (row0 + row)], n1 = nf[2 * (row0 + row) + 1];
#pragma unroll
            for (int j = 0; j < 16; ++j) v[j] = n0 * Wn[cb + j] + n1 * Wn[HID + cb + j];
            if (blockIdx.x == 0) {
#pragma unroll
                for (int j = 0; j < 16; j += 4)
                    *(float4*)&hout[(long)(row0 + row) * HID + cb + j] = *(float4*)&v[j];
            }
        } else {
            const float* xp = x + (long)(row0 + row) * HID + cb;
#pragma unroll
            for (int j = 0; j < 16; j += 4) *(float4*)&v[j] = *(const float4*)(xp + j);
            if (x2) {
                const float* yp = x2 + (long)(row0 + row) * HID + cb;
#pragma unroll
                for (int j = 0; j < 16; j += 4) {
                    float4 r4 = *(const float4*)(yp + j);
                    v[j] += r4.x; v[j+1] += r4.y; v[j+2] += r4.z; v[j+3] += r4.w;
                }
            }
        }
        float s = 0.f, s2 = 0.f;
#pragma unroll
        for (int j = 0; j < 16; ++j) { s += v[j]; s2 += v[j] * v[j]; }
        s  += __shfl_xor(s, 1);  s  += __shfl_xor(s, 2);  s  += __shfl_xor(s, 4);
        s2 += __shfl_xor(s2, 1); s2 += __shfl_xor(s2, 2); s2 += __shfl_xor(s2, 4);
        float mu  = s * (1.f / HID);
        float var = s2 * (1.f / HID) - mu * mu;
        float inv = rsqrtf(var + 1e-5f);
        unsigned short hi[16], lo[16];
#pragma unroll
        for (int j = 0; j < 16; ++j) {
            int c = cb + j;
            float o = (v[j] - mu) * inv * g[c] + b[c];
            hi[j] = f2b(o); lo[j] = f2b(o - us2f(hi[j]));
        }
        *(uint4*)&sAh[row * 136 + cb]     = *(uint4*)&hi[0];
        *(uint4*)&sAh[row * 136 + cb + 8] = *(uint4*)&hi[8];
        *(uint4*)&sAl[row * 136 + cb]     = *(uint4*)&lo[0];
        *(uint4*)&sAl[row * 136 + cb + 8] = *(uint4*)&lo[8];
    }
    // ---- store prefetched W planes to LDS
    {
        int rr0 = t >> 4, ck = t & 15;
#pragma unroll
        for (int p = 0; p < 4; ++p) {
            *(uint4*)&sWh[(rr0 + p * 16) * 136 + ck * 8] = wreg[p];
            *(uint4*)&sWl[(rr0 + p * 16) * 136 + ck * 8] = wreg[4 + p];
        }
    }
    __syncthreads();

    int w = t >> 6, lane = t & 63;
    int m = lane & 15, quad = lane >> 4;
    f32x4 acc[4];
#pragma unroll
    for (int i = 0; i < 4; ++i) acc[i] = (f32x4){0.f, 0.f, 0.f, 0.f};
#pragma unroll
    for (int c = 0; c < 4; ++c) {
        bf16x8 ah = *(const bf16x8*)&sAh[(w * 16 + m) * 136 + c * 32 + quad * 8];
        bf16x8 al = *(const bf16x8*)&sAl[(w * 16 + m) * 136 + c * 32 + quad * 8];
#pragma unroll
        for (int nt = 0; nt < 4; ++nt) {
            bf16x8 wh = *(const bf16x8*)&sWh[(nt * 16 + m) * 136 + c * 32 + quad * 8];
            bf16x8 wl = *(const bf16x8*)&sWl[(nt * 16 + m) * 136 + c * 32 + quad * 8];
            acc[nt] = __builtin_amdgcn_mfma_f32_16x16x32_bf16(ah, wh, acc[nt], 0, 0, 0);
            acc[nt] = __builtin_amdgcn_mfma_f32_16x16x32_bf16(ah, wl, acc[nt], 0, 0, 0);
            acc[nt] = __builtin_amdgcn_mfma_f32_16x16x32_bf16(al, wh, acc[nt], 0, 0, 0);
        }
    }
#pragma unroll
    for (int nt = 0; nt < 4; ++nt) {
#pragma unroll
        for (int r = 0; r < 4; ++r) {
            int row = row0 + w * 16 + quad * 4 + r;
            int col = col0 + nt * 16 + m;
            float v = acc[nt][r];
            if (mode == 0) {
                Cf[(long)row * Nc + col] = v;
            } else {
                v = fmaxf(v, 0.f);
                unsigned short hh = f2b(v);
                Ch[(long)row * Nc + col] = hh;
                Cl[(long)row * Nc + col] = f2b(v - us2f(hh));
            }
        }
    }
}

// ---------- W2 GEMM + residual: 16 rows x 64 cols per block, grid (2, 256).
__global__ __launch_bounds__(256, 4) void k_w2(
    const unsigned short* __restrict__ Ah, const unsigned short* __restrict__ Al,   // [4096][512]
    const unsigned short* __restrict__ WH, const unsigned short* __restrict__ WL,   // [128][512]
    const float* __restrict__ yres, float* __restrict__ hout)
{
    __shared__ unsigned short sA[2][16 * 72];    // 4.6 KB
    __shared__ unsigned short sW[2][64 * 72];    // 18.4 KB
    int t = threadIdx.x;
    int ct = blockIdx.x, row0 = blockIdx.y * 16, col0 = ct * 64;
    int w = t >> 6, lane = t & 63;
    int m = lane & 15, quad = lane >> 4;
    f32x4 acc = (f32x4){0.f, 0.f, 0.f, 0.f};

    for (int ks = 0; ks < 512; ks += 64) {
        if (ks) __syncthreads();
        {   // A planes: 16 rows x 64k x 2 planes = 256 uint4; one per thread
            int pl = t >> 7, tt = t & 127;
            int r = tt >> 3, ck = tt & 7;
            const unsigned short* src = pl ? Al : Ah;
            *(uint4*)&sA[pl][r * 72 + ck * 8] = *(const uint4*)&src[(long)(row0 + r) * 512 + ks + ck * 8];
        }
        {   // W planes: 64 n-rows x 64k x 2 planes; 4 uint4 per thread
            int n = t >> 2, c2 = (t & 3) * 2;
            *(uint4*)&sW[0][n * 72 + c2 * 8]       = *(const uint4*)&WH[(long)(col0 + n) * 512 + ks + c2 * 8];
            *(uint4*)&sW[0][n * 72 + (c2 + 1) * 8] = *(const uint4*)&WH[(long)(col0 + n) * 512 + ks + (c2 + 1) * 8];
            *(uint4*)&sW[1][n * 72 + c2 * 8]       = *(const uint4*)&WL[(long)(col0 + n) * 512 + ks + c2 * 8];
            *(uint4*)&sW[1][n * 72 + (c2 + 1) * 8] = *(const uint4*)&WL[(long)(col0 + n) * 512 + ks + (c2 + 1) * 8];
        }
        __syncthreads();
#pragma unroll
        for (int c = 0; c < 2; ++c) {
            bf16x8 ah = *(const bf16x8*)&sA[0][m * 72 + c * 32 + quad * 8];
            bf16x8 al = *(const bf16x8*)&sA[1][m * 72 + c * 32 + quad * 8];
            bf16x8 wh = *(const bf16x8*)&sW[0][(w * 16 + m) * 72 + c * 32 + quad * 8];
            bf16x8 wl = *(const bf16x8*)&sW[1][(w * 16 + m) * 72 + c * 32 + quad * 8];
            acc = __builtin_amdgcn_mfma_f32_16x16x32_bf16(ah, wh, acc, 0, 0, 0);
            acc = __builtin_amdgcn_mfma_f32_16x16x32_bf16(ah, wl, acc, 0, 0, 0);
            acc = __builtin_amdgcn_mfma_f32_16x16x32_bf16(al, wh, acc, 0, 0, 0);
        }
    }
#pragma unroll
    for (int r = 0; r < 4; ++r) {
        int row = row0 + quad * 4 + r;
        int col = col0 + w * 16 + m;
        hout[(long)row * HID + col] = acc[r] + yres[(long)row * HID + col];
    }
}

// ---------- attention: grid 512 = b x head x quarter; 4 waves x 16 q-rows.
// QK^T + softmax (no max-sub: LN-bounded scores) fp32 VALU; PV via split-bf16 MFMA.
// Defensive barrier before PV (closes the latent Pa RAW scheduling hazard).
#define PAS (NS + 8)
__global__ __launch_bounds__(256) void k_attn(const float* __restrict__ qkv,
                                              const float* __restrict__ ef,
                                              const float* __restrict__ sbuf,
                                              int layer,
                                              float* __restrict__ y) {
    __shared__ float Ks[NS][20];                     // 20.5 KB
    __shared__ unsigned short Vh[16][PAS];           // [d][key]
    __shared__ unsigned short Vl[16][PAS];
    __shared__ unsigned short Pa[4][16][PAS];        // per-wave [qrow][key]
    int bid = blockIdx.x;
    int q4 = bid & 3, hh = (bid >> 2) & 7, bb = bid >> 5;
    int t = threadIdx.x;
    {   // stage K fp32 + V bf16 hi/lo transposed
        const float* kr = qkv + ((long)(bb * NS + t)) * 384 + HID + hh * 16;
        *(float4*)&Ks[t][0]  = *(const float4*)kr;
        *(float4*)&Ks[t][4]  = *(const float4*)(kr + 4);
        *(float4*)&Ks[t][8]  = *(const float4*)(kr + 8);
        *(float4*)&Ks[t][12] = *(const float4*)(kr + 12);
        const float* vr = kr + HID;
        float vv[16];
        *(float4*)&vv[0]  = *(const float4*)vr;
        *(float4*)&vv[4]  = *(const float4*)(vr + 4);
        *(float4*)&vv[8]  = *(const float4*)(vr + 8);
        *(float4*)&vv[12] = *(const float4*)(vr + 12);
#pragma unroll
        for (int d = 0; d < 16; ++d) {
            unsigned short hi = f2b(vv[d]);
            Vh[d][t] = hi;
            Vl[d][t] = f2b(vv[d] - us2f(hi));
        }
    }
    __syncthreads();
    int w = t >> 6, lane = t & 63;
    float s1  = sbuf[layer * 16 + hh];
    float s2g = sbuf[layer * 16 + NHEAD + hh];
    int m = lane & 15, quad = lane >> 4;
    unsigned short* Paw = &Pa[w][0][0];
    for (int it = 0; it < 4; ++it) {
        int r0 = q4 * 64 + w * 16 + it * 4;
        float q[4][16];
#pragma unroll
        for (int rr = 0; rr < 4; ++rr) {
            const float* qr = qkv + ((long)(bb * NS + r0 + rr)) * 384 + hh * 16;
            *(float4*)&q[rr][0]  = *(const float4*)qr;
            *(float4*)&q[rr][4]  = *(const float4*)(qr + 4);
            *(float4*)&q[rr][8]  = *(const float4*)(qr + 8);
            *(float4*)&q[rr][12] = *(const float4*)(qr + 12);
        }
        float sc[4][4];
#pragma unroll
        for (int i = 0; i < 4; ++i) {
            int c = i * 64 + lane;
            float kk[16];
            *(float4*)&kk[0]  = *(const float4*)&Ks[c][0];
            *(float4*)&kk[4]  = *(const float4*)&Ks[c][4];
            *(float4*)&kk[8]  = *(const float4*)&Ks[c][8];
            *(float4*)&kk[12] = *(const float4*)&Ks[c][12];
#pragma unroll
            for (int rr = 0; rr < 4; ++rr) {
                float d0 = 0.f;
#pragma unroll
                for (int d = 0; d < 16; ++d) d0 += q[rr][d] * kk[d];
                sc[rr][i] = d0;
            }
        }
#pragma unroll
        for (int rr = 0; rr < 4; ++rr) {
            long eb = ((long)(bb * NS + r0 + rr)) * NS;
            float e0 = ef[eb + lane],       e1 = ef[eb + 64 + lane];
            float e2 = ef[eb + 128 + lane], e3 = ef[eb + 192 + lane];
            // no max-subtraction: scores LN-bounded far below fp32 exp overflow
            float p0 = __expf(sc[rr][0] * 0.25f + e0 * s1);
            float p1 = __expf(sc[rr][1] * 0.25f + e1 * s1);
            float p2 = __expf(sc[rr][2] * 0.25f + e2 * s1);
            float p3 = __expf(sc[rr][3] * 0.25f + e3 * s1);
            float sum = p0 + p1 + p2 + p3;
#pragma unroll
            for (int o = 32; o; o >>= 1) sum += __shfl_xor(sum, o);
            float inv = s2g / sum;
            int prow = it * 4 + rr;
            Paw[prow * PAS + lane]       = f2b(p0 * inv * e0);
            Paw[prow * PAS + 64 + lane]  = f2b(p1 * inv * e1);
            Paw[prow * PAS + 128 + lane] = f2b(p2 * inv * e2);
            Paw[prow * PAS + 192 + lane] = f2b(p3 * inv * e3);
        }
    }
    __syncthreads();   // guarantee all Pa writes visible before PV MFMA reads
    // PV via MFMA
    f32x4 acc = (f32x4){0.f, 0.f, 0.f, 0.f};
#pragma unroll
    for (int s = 0; s < 8; ++s) {
        bf16x8 pf = *(const bf16x8*)&Paw[m * PAS + s * 32 + quad * 8];
        bf16x8 vh = *(const bf16x8*)&Vh[m][s * 32 + quad * 8];
        bf16x8 vl = *(const bf16x8*)&Vl[m][s * 32 + quad * 8];
        acc = __builtin_amdgcn_mfma_f32_16x16x32_bf16(pf, vh, acc, 0, 0, 0);
        acc = __builtin_amdgcn_mfma_f32_16x16x32_bf16(pf, vl, acc, 0, 0, 0);
    }
#pragma unroll
    for (int r = 0; r < 4; ++r) {
        int row = q4 * 64 + w * 16 + quad * 4 + r;
        y[((long)(bb * NS + row)) * HID + hh * 16 + m] = acc[r];
    }
}

// ---------- out = 10*tanh((h @ Wdec)/sqrt(128)), one wave per row
__global__ __launch_bounds__(256) void k_dec(const float* __restrict__ h,
                                             const float* __restrict__ Wdec,
                                             float* __restrict__ out) {
    int w = threadIdx.x >> 6, lane = threadIdx.x & 63;
    int row = blockIdx.x * 4 + w;
    float a = h[(long)row * HID + lane] * Wdec[lane]
            + h[(long)row * HID + 64 + lane] * Wdec[64 + lane];
#pragma unroll
    for (int o = 32; o; o >>= 1) a += __shfl_xor(a, o);
    if (lane == 0) out[row] = 10.f * tanhf(a * 0.08838834764831845f);
}

extern "C" void kernel_launch(void* const* d_in, const int* in_sizes, int n_in,
                              void* d_out, int out_size, void* d_ws, size_t ws_size,
                              hipStream_t stream) {
    const float* nf    = (const float*)d_in[0];
    const float* ef    = (const float*)d_in[1];
    const float* Wn    = (const float*)d_in[2];
    const float* We_in = (const float*)d_in[3];
    const float* ln1g  = (const float*)d_in[4];
    const float* ln1b  = (const float*)d_in[5];
    const float* Wh    = (const float*)d_in[6];
    const float* We    = (const float*)d_in[7];
    const float* ln2g  = (const float*)d_in[8];
    const float* ln2b  = (const float*)d_in[9];
    const float* W1    = (const float*)d_in[10];
    const float* W2    = (const float*)d_in[11];
    const float* Wdec  = (const float*)d_in[12];

    float* ws   = (float*)d_ws;
    float* sbuf = ws;                            // 64 slots
    float* h    = ws + 64;                       // 4096*128
    float* y    = h + ROWS * HID;                // 4096*128
    float* qkv  = y + ROWS * HID;                // 4096*384
    unsigned short* hidH = (unsigned short*)(qkv + (long)ROWS * 384);   // 4096*512
    unsigned short* hidL = hidH + (long)ROWS * 512;
    unsigned short* WhH  = hidL + (long)ROWS * 512;          // 3*384*128
    unsigned short* WhL  = WhH + (long)NL * 384 * 128;
    unsigned short* W1H  = WhL + (long)NL * 384 * 128;       // 3*512*128
    unsigned short* W1L  = W1H + (long)NL * 512 * 128;
    unsigned short* W2H  = W1L + (long)NL * 512 * 128;       // 3*128*512
    unsigned short* W2L  = W2H + (long)NL * 128 * 512;

    k_prep<<<529, 256, 0, stream>>>(Wh, W1, W2, We_in, We,
                                    WhH, WhL, W1H, W1L, W2H, W2L, sbuf);
    for (int l = 0; l < NL; ++l) {
        // LN1 + QKV GEMM (layer 0: embed fused in-register, col-block 0 writes h)
        k_fgemm<<<dim3(6, 64), 256, 0, stream>>>(h, nullptr,
            (l == 0) ? nf : nullptr, Wn, h,
            ln1g + l * HID, ln1b + l * HID,
            WhH + (long)l * 384 * 128, WhL + (long)l * 384 * 128,
            qkv, nullptr, nullptr, 384, 0);
        k_attn<<<512, 256, 0, stream>>>(qkv, ef, sbuf, l, y);
        // LN2(y+h) + W1 GEMM + relu -> planes
        k_fgemm<<<dim3(8, 64), 256, 0, stream>>>(y, h,
            nullptr, Wn, nullptr,
            ln2g + l * HID, ln2b + l * HID,
            W1H + (long)l * 512 * 128, W1L + (long)l * 512 * 128,
            nullptr, hidH, hidL, 512, 1);
        // W2 GEMM + residual -> h
        k_w2<<<dim3(2, 256), 256, 0, stream>>>(hidH, hidL,
            W2H + (long)l * 128 * 512, W2L + (long)l * 128 * 512, y, h);
    }
    k_dec<<<ROWS / 4, 256, 0, stream>>>(h, Wdec, (float*)d_out);
}

// Round 13
// 225.257 us; speedup vs baseline: 1.1117x; 1.1117x over previous
//
#include <hip/hip_runtime.h>
#include <math.h>

#define HID 128
#define NHEAD 8
#define NL 3
#define NS 256
#define ROWS 4096

typedef __attribute__((ext_vector_type(8))) short bf16x8;
typedef __attribute__((ext_vector_type(4))) float f32x4;

__device__ __forceinline__ float us2f(unsigned short s) { return __uint_as_float(((unsigned)s) << 16); }
__device__ __forceinline__ unsigned short f2b(float f) {   // RNE fp32->bf16
    unsigned u = __float_as_uint(f);
    return (unsigned short)((u + 0x7fff + ((u >> 16) & 1)) >> 16);
}

// ---------- prep: weight split+transpose to bf16 hi/lo planes [N][K] + edge scalars + embed
// blocks: [0,144) Wh, [144,336) W1, [336,528) W2, 528 edge scalars, [529,2577) embed h=nf@Wn
__global__ __launch_bounds__(256) void k_prep(
    const float* __restrict__ Wh, const float* __restrict__ W1, const float* __restrict__ W2,
    const float* __restrict__ We_in, const float* __restrict__ We,
    const float* __restrict__ nf, const float* __restrict__ Wn,
    unsigned short* __restrict__ WhH, unsigned short* __restrict__ WhL,
    unsigned short* __restrict__ W1H, unsigned short* __restrict__ W1L,
    unsigned short* __restrict__ W2H, unsigned short* __restrict__ W2L,
    float* __restrict__ sbuf, float* __restrict__ h)
{
    int b = blockIdx.x, t = threadIdx.x;
    if (b >= 529) {                       // embed
        int idx = (b - 529) * 256 + t;
        int r = idx >> 7, c = idx & 127;
        h[idx] = nf[2 * r] * Wn[c] + nf[2 * r + 1] * Wn[HID + c];
        return;
    }
    if (b == 528) {                       // edge scalars (rank-1 collapse of e @ We)
        if (t < NL * 2 * NHEAD) {
            int l = t / (2 * NHEAD), j = t % (2 * NHEAD);
            float acc = 0.f;
            for (int c = 0; c < HID; ++c)
                acc += We_in[c] * We[(long)(l * HID + c) * (2 * NHEAD) + j];
            sbuf[t] = acc;
        }
        return;
    }
    const float* S; unsigned short *OH, *OL; int K, N, kt, nt;
    if (b < 144) {
        int l = b / 48, rem = b % 48; kt = rem & 3; nt = rem >> 2; K = 128; N = 384;
        S = Wh + (long)l * 128 * 384; OH = WhH + (long)l * 384 * 128; OL = WhL + (long)l * 384 * 128;
    } else if (b < 336) {
        int b2 = b - 144; int l = b2 / 64, rem = b2 % 64; kt = rem & 3; nt = rem >> 2; K = 128; N = 512;
        S = W1 + (long)l * 128 * 512; OH = W1H + (long)l * 512 * 128; OL = W1L + (long)l * 512 * 128;
    } else {
        int b2 = b - 336; int l = b2 / 64, rem = b2 % 64; kt = rem & 15; nt = rem >> 4; K = 512; N = 128;
        S = W2 + (long)l * 512 * 128; OH = W2H + (long)l * 128 * 512; OL = W2L + (long)l * 128 * 512;
    }
    __shared__ float sm[32][33];
    int i0 = t >> 5, j = t & 31;
#pragma unroll
    for (int p = 0; p < 4; ++p) {
        int i = i0 + p * 8;
        sm[i][j] = S[(long)(kt * 32 + i) * N + nt * 32 + j];
    }
    __syncthreads();
#pragma unroll
    for (int p = 0; p < 4; ++p) {
        int n = i0 + p * 8;
        float v = sm[j][n];
        unsigned short hh = f2b(v);
        long o = (long)(nt * 32 + n) * K + kt * 32 + j;
        OH[o] = hh; OL[o] = f2b(v - us2f(hh));
    }
}

// ---------- fused LN + split-bf16 MFMA GEMM, K=128 single-shot, 64x64 tile, 4 waves.
// mode 0: Cf = acc     mode 1: relu -> Ch/Cl planes
__global__ __launch_bounds__(256) void k_fgemm(
    const float* __restrict__ x, const float* __restrict__ x2,
    const float* __restrict__ g, const float* __restrict__ b,
    const unsigned short* __restrict__ WH, const unsigned short* __restrict__ WL,
    float* __restrict__ Cf, unsigned short* __restrict__ Ch, unsigned short* __restrict__ Cl,
    int Nc, int mode)
{
    __shared__ unsigned short sAh[64 * 136], sAl[64 * 136];   // [m][k]
    __shared__ unsigned short sWh[64 * 136], sWl[64 * 136];   // [n][k]
    int t = threadIdx.x;
    int row0 = blockIdx.y * 64, col0 = blockIdx.x * 64;

#pragma unroll
    for (int p = 0; p < 4; ++p) {
        int rr = (t >> 4) + p * 16, ck = t & 15;
        *(uint4*)&sWh[rr * 136 + ck * 8] = *(const uint4*)&WH[(long)(col0 + rr) * 128 + ck * 8];
        *(uint4*)&sWl[rr * 136 + ck * 8] = *(const uint4*)&WL[(long)(col0 + rr) * 128 + ck * 8];
    }
#pragma unroll
    for (int pass = 0; pass < 2; ++pass) {
        int row = pass * 32 + (t >> 3);
        int p = t & 7, cb = p * 16;
        float v[16];
        const float* xp = x + (long)(row0 + row) * HID + cb;
#pragma unroll
        for (int j = 0; j < 16; j += 4) *(float4*)&v[j] = *(const float4*)(xp + j);
        if (x2) {
            const float* yp = x2 + (long)(row0 + row) * HID + cb;
#pragma unroll
            for (int j = 0; j < 16; j += 4) {
                float4 r4 = *(const float4*)(yp + j);
                v[j] += r4.x; v[j+1] += r4.y; v[j+2] += r4.z; v[j+3] += r4.w;
            }
        }
        float s = 0.f, s2 = 0.f;
#pragma unroll
        for (int j = 0; j < 16; ++j) { s += v[j]; s2 += v[j] * v[j]; }
        s  += __shfl_xor(s, 1);  s  += __shfl_xor(s, 2);  s  += __shfl_xor(s, 4);
        s2 += __shfl_xor(s2, 1); s2 += __shfl_xor(s2, 2); s2 += __shfl_xor(s2, 4);
        float mu  = s * (1.f / HID);
        float var = s2 * (1.f / HID) - mu * mu;
        float inv = rsqrtf(var + 1e-5f);
        unsigned short hi[16], lo[16];
#pragma unroll
        for (int j = 0; j < 16; ++j) {
            int c = cb + j;
            float o = (v[j] - mu) * inv * g[c] + b[c];
            hi[j] = f2b(o); lo[j] = f2b(o - us2f(hi[j]));
        }
        *(uint4*)&sAh[row * 136 + cb]     = *(uint4*)&hi[0];
        *(uint4*)&sAh[row * 136 + cb + 8] = *(uint4*)&hi[8];
        *(uint4*)&sAl[row * 136 + cb]     = *(uint4*)&lo[0];
        *(uint4*)&sAl[row * 136 + cb + 8] = *(uint4*)&lo[8];
    }
    __syncthreads();

    int w = t >> 6, lane = t & 63;
    int m = lane & 15, quad = lane >> 4;
    f32x4 acc[4];
#pragma unroll
    for (int i = 0; i < 4; ++i) acc[i] = (f32x4){0.f, 0.f, 0.f, 0.f};
#pragma unroll
    for (int c = 0; c < 4; ++c) {
        bf16x8 ah = *(const bf16x8*)&sAh[(w * 16 + m) * 136 + c * 32 + quad * 8];
        bf16x8 al = *(const bf16x8*)&sAl[(w * 16 + m) * 136 + c * 32 + quad * 8];
#pragma unroll
        for (int nt = 0; nt < 4; ++nt) {
            bf16x8 wh = *(const bf16x8*)&sWh[(nt * 16 + m) * 136 + c * 32 + quad * 8];
            bf16x8 wl = *(const bf16x8*)&sWl[(nt * 16 + m) * 136 + c * 32 + quad * 8];
            acc[nt] = __builtin_amdgcn_mfma_f32_16x16x32_bf16(ah, wh, acc[nt], 0, 0, 0);
            acc[nt] = __builtin_amdgcn_mfma_f32_16x16x32_bf16(ah, wl, acc[nt], 0, 0, 0);
            acc[nt] = __builtin_amdgcn_mfma_f32_16x16x32_bf16(al, wh, acc[nt], 0, 0, 0);
        }
    }
#pragma unroll
    for (int nt = 0; nt < 4; ++nt) {
#pragma unroll
        for (int r = 0; r < 4; ++r) {
            int row = row0 + w * 16 + quad * 4 + r;
            int col = col0 + nt * 16 + m;
            float v = acc[nt][r];
            if (mode == 0) {
                Cf[(long)row * Nc + col] = v;
            } else {
                v = fmaxf(v, 0.f);
                unsigned short hh = f2b(v);
                Ch[(long)row * Nc + col] = hh;
                Cl[(long)row * Nc + col] = f2b(v - us2f(hh));
            }
        }
    }
}

// ---------- W2 GEMM + residual (+ fused decode on last layer): 16 rows x 128 cols/block.
__global__ __launch_bounds__(256, 3) void k_w2ln(
    const unsigned short* __restrict__ Ah, const unsigned short* __restrict__ Al,   // [4096][512]
    const unsigned short* __restrict__ WH, const unsigned short* __restrict__ WL,   // [128][512]
    const float* __restrict__ yres, float* __restrict__ hout,
    const float* __restrict__ Wdec, float* __restrict__ out)
{
    __shared__ unsigned short sA[2][16 * 72];
    __shared__ unsigned short sW[2][128 * 72];
    int t = threadIdx.x;
    int row0 = blockIdx.x * 16;
    int w = t >> 6, lane = t & 63;
    int m = lane & 15, quad = lane >> 4;
    f32x4 acc[2];
    acc[0] = (f32x4){0.f,0.f,0.f,0.f}; acc[1] = (f32x4){0.f,0.f,0.f,0.f};

    for (int ks = 0; ks < 512; ks += 64) {
        if (ks) __syncthreads();
        {
            int pl = t >> 7, tt = t & 127;
            int r = tt >> 3, ck = tt & 7;
            const unsigned short* src = pl ? Al : Ah;
            *(uint4*)&sA[pl][r * 72 + ck * 8] = *(const uint4*)&src[(long)(row0 + r) * 512 + ks + ck * 8];
        }
        {
            int r0 = t >> 3, ck = t & 7;
#pragma unroll
            for (int p = 0; p < 4; ++p) {
                int n = r0 + p * 32;
                *(uint4*)&sW[0][n * 72 + ck * 8] = *(const uint4*)&WH[(long)n * 512 + ks + ck * 8];
                *(uint4*)&sW[1][n * 72 + ck * 8] = *(const uint4*)&WL[(long)n * 512 + ks + ck * 8];
            }
        }
        __syncthreads();
#pragma unroll
        for (int c = 0; c < 2; ++c) {
            bf16x8 ah = *(const bf16x8*)&sA[0][m * 72 + c * 32 + quad * 8];
            bf16x8 al = *(const bf16x8*)&sA[1][m * 72 + c * 32 + quad * 8];
#pragma unroll
            for (int nt = 0; nt < 2; ++nt) {
                int n = w * 32 + nt * 16 + m;
                bf16x8 wh = *(const bf16x8*)&sW[0][n * 72 + c * 32 + quad * 8];
                bf16x8 wl = *(const bf16x8*)&sW[1][n * 72 + c * 32 + quad * 8];
                acc[nt] = __builtin_amdgcn_mfma_f32_16x16x32_bf16(ah, wh, acc[nt], 0, 0, 0);
                acc[nt] = __builtin_amdgcn_mfma_f32_16x16x32_bf16(ah, wl, acc[nt], 0, 0, 0);
                acc[nt] = __builtin_amdgcn_mfma_f32_16x16x32_bf16(al, wh, acc[nt], 0, 0, 0);
            }
        }
    }
    __syncthreads();                    // all sW reads done; reuse as fp32 tile
    float* ht = (float*)&sW[0][0];      // [16][132]
#pragma unroll
    for (int nt = 0; nt < 2; ++nt) {
#pragma unroll
        for (int r = 0; r < 4; ++r) {
            int row = quad * 4 + r;
            int col = w * 32 + nt * 16 + m;
            float v = acc[nt][r] + yres[(long)(row0 + row) * HID + col];
            hout[(long)(row0 + row) * HID + col] = v;
            ht[row * 132 + col] = v;
        }
    }
    __syncthreads();
    if (Wdec) {                         // fused decode: out = 10*tanh((h@Wdec)/sqrt(128))
        int row = t >> 4, sub = t & 15;
        float v[8];
        *(float4*)&v[0] = *(const float4*)&ht[row * 132 + sub * 8];
        *(float4*)&v[4] = *(const float4*)&ht[row * 132 + sub * 8 + 4];
        float a = 0.f;
#pragma unroll
        for (int j = 0; j < 8; ++j) a += v[j] * Wdec[sub * 8 + j];
        a += __shfl_xor(a, 1); a += __shfl_xor(a, 2); a += __shfl_xor(a, 4); a += __shfl_xor(a, 8);
        if (sub == 0) out[row0 + row] = 10.f * tanhf(a * 0.08838834764831845f);
    }
}

// ---------- attention: grid 512 = b x head x quarter; 4 waves x 16 q-rows.
// QK^T + softmax (no max-sub: LN-bounded scores) fp32 VALU; PV via split-bf16 MFMA.
// Defensive barrier before PV (closes the latent Pa RAW scheduling hazard).
#define PAS (NS + 8)
__global__ __launch_bounds__(256) void k_attn(const float* __restrict__ qkv,
                                              const float* __restrict__ ef,
                                              const float* __restrict__ sbuf,
                                              int layer,
                                              float* __restrict__ y) {
    __shared__ float Ks[NS][20];                     // 20.5 KB
    __shared__ unsigned short Vh[16][PAS];           // [d][key]
    __shared__ unsigned short Vl[16][PAS];
    __shared__ unsigned short Pa[4][16][PAS];        // per-wave [qrow][key]
    int bid = blockIdx.x;
    int q4 = bid & 3, hh = (bid >> 2) & 7, bb = bid >> 5;
    int t = threadIdx.x;
    {   // stage K fp32 + V bf16 hi/lo transposed
        const float* kr = qkv + ((long)(bb * NS + t)) * 384 + HID + hh * 16;
        *(float4*)&Ks[t][0]  = *(const float4*)kr;
        *(float4*)&Ks[t][4]  = *(const float4*)(kr + 4);
        *(float4*)&Ks[t][8]  = *(const float4*)(kr + 8);
        *(float4*)&Ks[t][12] = *(const float4*)(kr + 12);
        const float* vr = kr + HID;
        float vv[16];
        *(float4*)&vv[0]  = *(const float4*)vr;
        *(float4*)&vv[4]  = *(const float4*)(vr + 4);
        *(float4*)&vv[8]  = *(const float4*)(vr + 8);
        *(float4*)&vv[12] = *(const float4*)(vr + 12);
#pragma unroll
        for (int d = 0; d < 16; ++d) {
            unsigned short hi = f2b(vv[d]);
            Vh[d][t] = hi;
            Vl[d][t] = f2b(vv[d] - us2f(hi));
        }
    }
    __syncthreads();
    int w = t >> 6, lane = t & 63;
    float s1  = sbuf[layer * 16 + hh];
    float s2g = sbuf[layer * 16 + NHEAD + hh];
    int m = lane & 15, quad = lane >> 4;
    unsigned short* Paw = &Pa[w][0][0];
    for (int it = 0; it < 4; ++it) {
        int r0 = q4 * 64 + w * 16 + it * 4;
        float q[4][16];
#pragma unroll
        for (int rr = 0; rr < 4; ++rr) {
            const float* qr = qkv + ((long)(bb * NS + r0 + rr)) * 384 + hh * 16;
            *(float4*)&q[rr][0]  = *(const float4*)qr;
            *(float4*)&q[rr][4]  = *(const float4*)(qr + 4);
            *(float4*)&q[rr][8]  = *(const float4*)(qr + 8);
            *(float4*)&q[rr][12] = *(const float4*)(qr + 12);
        }
        float sc[4][4];
#pragma unroll
        for (int i = 0; i < 4; ++i) {
            int c = i * 64 + lane;
            float kk[16];
            *(float4*)&kk[0]  = *(const float4*)&Ks[c][0];
            *(float4*)&kk[4]  = *(const float4*)&Ks[c][4];
            *(float4*)&kk[8]  = *(const float4*)&Ks[c][8];
            *(float4*)&kk[12] = *(const float4*)&Ks[c][12];
#pragma unroll
            for (int rr = 0; rr < 4; ++rr) {
                float d0 = 0.f;
#pragma unroll
                for (int d = 0; d < 16; ++d) d0 += q[rr][d] * kk[d];
                sc[rr][i] = d0;
            }
        }
#pragma unroll
        for (int rr = 0; rr < 4; ++rr) {
            long eb = ((long)(bb * NS + r0 + rr)) * NS;
            float e0 = ef[eb + lane],       e1 = ef[eb + 64 + lane];
            float e2 = ef[eb + 128 + lane], e3 = ef[eb + 192 + lane];
            // no max-subtraction: scores LN-bounded far below fp32 exp overflow
            float p0 = __expf(sc[rr][0] * 0.25f + e0 * s1);
            float p1 = __expf(sc[rr][1] * 0.25f + e1 * s1);
            float p2 = __expf(sc[rr][2] * 0.25f + e2 * s1);
            float p3 = __expf(sc[rr][3] * 0.25f + e3 * s1);
            float sum = p0 + p1 + p2 + p3;
#pragma unroll
            for (int o = 32; o; o >>= 1) sum += __shfl_xor(sum, o);
            float inv = s2g / sum;
            int prow = it * 4 + rr;
            Paw[prow * PAS + lane]       = f2b(p0 * inv * e0);
            Paw[prow * PAS + 64 + lane]  = f2b(p1 * inv * e1);
            Paw[prow * PAS + 128 + lane] = f2b(p2 * inv * e2);
            Paw[prow * PAS + 192 + lane] = f2b(p3 * inv * e3);
        }
    }
    __syncthreads();   // guarantee all Pa writes visible before PV MFMA reads
    // PV via MFMA
    f32x4 acc = (f32x4){0.f, 0.f, 0.f, 0.f};
#pragma unroll
    for (int s = 0; s < 8; ++s) {
        bf16x8 pf = *(const bf16x8*)&Paw[m * PAS + s * 32 + quad * 8];
        bf16x8 vh = *(const bf16x8*)&Vh[m][s * 32 + quad * 8];
        bf16x8 vl = *(const bf16x8*)&Vl[m][s * 32 + quad * 8];
        acc = __builtin_amdgcn_mfma_f32_16x16x32_bf16(pf, vh, acc, 0, 0, 0);
        acc = __builtin_amdgcn_mfma_f32_16x16x32_bf16(pf, vl, acc, 0, 0, 0);
    }
#pragma unroll
    for (int r = 0; r < 4; ++r) {
        int row = q4 * 64 + w * 16 + quad * 4 + r;
        y[((long)(bb * NS + row)) * HID + hh * 16 + m] = acc[r];
    }
}

extern "C" void kernel_launch(void* const* d_in, const int* in_sizes, int n_in,
                              void* d_out, int out_size, void* d_ws, size_t ws_size,
                              hipStream_t stream) {
    const float* nf    = (const float*)d_in[0];
    const float* ef    = (const float*)d_in[1];
    const float* Wn    = (const float*)d_in[2];
    const float* We_in = (const float*)d_in[3];
    const float* ln1g  = (const float*)d_in[4];
    const float* ln1b  = (const float*)d_in[5];
    const float* Wh    = (const float*)d_in[6];
    const float* We    = (const float*)d_in[7];
    const float* ln2g  = (const float*)d_in[8];
    const float* ln2b  = (const float*)d_in[9];
    const float* W1    = (const float*)d_in[10];
    const float* W2    = (const float*)d_in[11];
    const float* Wdec  = (const float*)d_in[12];

    float* ws   = (float*)d_ws;
    float* sbuf = ws;                            // 64 slots
    float* h    = ws + 64;                       // 4096*128
    float* y    = h + ROWS * HID;                // 4096*128
    float* qkv  = y + ROWS * HID;                // 4096*384
    unsigned short* hidH = (unsigned short*)(qkv + (long)ROWS * 384);   // 4096*512
    unsigned short* hidL = hidH + (long)ROWS * 512;
    unsigned short* WhH  = hidL + (long)ROWS * 512;          // 3*384*128
    unsigned short* WhL  = WhH + (long)NL * 384 * 128;
    unsigned short* W1H  = WhL + (long)NL * 384 * 128;       // 3*512*128
    unsigned short* W1L  = W1H + (long)NL * 512 * 128;
    unsigned short* W2H  = W1L + (long)NL * 512 * 128;       // 3*128*512
    unsigned short* W2L  = W2H + (long)NL * 128 * 512;

    k_prep<<<529 + ROWS * HID / 256, 256, 0, stream>>>(Wh, W1, W2, We_in, We, nf, Wn,
                                    WhH, WhL, W1H, W1L, W2H, W2L, sbuf, h);
    for (int l = 0; l < NL; ++l) {
        // LN1 + QKV GEMM
        k_fgemm<<<dim3(6, 64), 256, 0, stream>>>(h, nullptr,
            ln1g + l * HID, ln1b + l * HID,
            WhH + (long)l * 384 * 128, WhL + (long)l * 384 * 128,
            qkv, nullptr, nullptr, 384, 0);
        k_attn<<<512, 256, 0, stream>>>(qkv, ef, sbuf, l, y);
        // LN2(y+h) + W1 GEMM + relu -> planes
        k_fgemm<<<dim3(8, 64), 256, 0, stream>>>(y, h,
            ln2g + l * HID, ln2b + l * HID,
            W1H + (long)l * 512 * 128, W1L + (long)l * 512 * 128,
            nullptr, hidH, hidL, 512, 1);
        // W2 GEMM + residual -> h (+ decode on last layer)
        int last = (l == NL - 1);
        k_w2ln<<<ROWS / 16, 256, 0, stream>>>(hidH, hidL,
            W2H + (long)l * 128 * 512, W2L + (long)l * 128 * 512,
            y, h, last ? Wdec : nullptr, (float*)d_out);
    }
}

// Round 14
// 218.149 us; speedup vs baseline: 1.1480x; 1.0326x over previous
//
#include <hip/hip_runtime.h>
#include <math.h>

#define HID 128
#define NHEAD 8
#define NL 3
#define NS 256
#define ROWS 4096

typedef __attribute__((ext_vector_type(8))) short bf16x8;
typedef __attribute__((ext_vector_type(4))) float f32x4;

__device__ __forceinline__ float us2f(unsigned short s) { return __uint_as_float(((unsigned)s) << 16); }
__device__ __forceinline__ unsigned short f2b(float f) {   // RNE fp32->bf16
    unsigned u = __float_as_uint(f);
    return (unsigned short)((u + 0x7fff + ((u >> 16) & 1)) >> 16);
}

// ---------- prep: weight split+transpose to bf16 hi/lo planes [N][K] + edge scalars + embed
// blocks: [0,144) Wh, [144,336) W1, [336,528) W2, 528 edge scalars, [529,2577) embed h=nf@Wn
__global__ __launch_bounds__(256) void k_prep(
    const float* __restrict__ Wh, const float* __restrict__ W1, const float* __restrict__ W2,
    const float* __restrict__ We_in, const float* __restrict__ We,
    const float* __restrict__ nf, const float* __restrict__ Wn,
    unsigned short* __restrict__ WhH, unsigned short* __restrict__ WhL,
    unsigned short* __restrict__ W1H, unsigned short* __restrict__ W1L,
    unsigned short* __restrict__ W2H, unsigned short* __restrict__ W2L,
    float* __restrict__ sbuf, float* __restrict__ h)
{
    int b = blockIdx.x, t = threadIdx.x;
    if (b >= 529) {                       // embed
        int idx = (b - 529) * 256 + t;
        int r = idx >> 7, c = idx & 127;
        h[idx] = nf[2 * r] * Wn[c] + nf[2 * r + 1] * Wn[HID + c];
        return;
    }
    if (b == 528) {                       // edge scalars (rank-1 collapse of e @ We)
        if (t < NL * 2 * NHEAD) {
            int l = t / (2 * NHEAD), j = t % (2 * NHEAD);
            float acc = 0.f;
            for (int c = 0; c < HID; ++c)
                acc += We_in[c] * We[(long)(l * HID + c) * (2 * NHEAD) + j];
            sbuf[t] = acc;
        }
        return;
    }
    const float* S; unsigned short *OH, *OL; int K, N, kt, nt;
    if (b < 144) {
        int l = b / 48, rem = b % 48; kt = rem & 3; nt = rem >> 2; K = 128; N = 384;
        S = Wh + (long)l * 128 * 384; OH = WhH + (long)l * 384 * 128; OL = WhL + (long)l * 384 * 128;
    } else if (b < 336) {
        int b2 = b - 144; int l = b2 / 64, rem = b2 % 64; kt = rem & 3; nt = rem >> 2; K = 128; N = 512;
        S = W1 + (long)l * 128 * 512; OH = W1H + (long)l * 512 * 128; OL = W1L + (long)l * 512 * 128;
    } else {
        int b2 = b - 336; int l = b2 / 64, rem = b2 % 64; kt = rem & 15; nt = rem >> 4; K = 512; N = 128;
        S = W2 + (long)l * 512 * 128; OH = W2H + (long)l * 128 * 512; OL = W2L + (long)l * 128 * 512;
    }
    __shared__ float sm[32][33];
    int i0 = t >> 5, j = t & 31;
#pragma unroll
    for (int p = 0; p < 4; ++p) {
        int i = i0 + p * 8;
        sm[i][j] = S[(long)(kt * 32 + i) * N + nt * 32 + j];
    }
    __syncthreads();
#pragma unroll
    for (int p = 0; p < 4; ++p) {
        int n = i0 + p * 8;
        float v = sm[j][n];
        unsigned short hh = f2b(v);
        long o = (long)(nt * 32 + n) * K + kt * 32 + j;
        OH[o] = hh; OL[o] = f2b(v - us2f(hh));
    }
}

// ---------- fused LN + split-bf16 MFMA GEMM, K=128 single-shot, 64x64 tile, 4 waves.
// mode 0: Cf = acc     mode 1: relu -> Ch/Cl planes
__global__ __launch_bounds__(256) void k_fgemm(
    const float* __restrict__ x, const float* __restrict__ x2,
    const float* __restrict__ g, const float* __restrict__ b,
    const unsigned short* __restrict__ WH, const unsigned short* __restrict__ WL,
    float* __restrict__ Cf, unsigned short* __restrict__ Ch, unsigned short* __restrict__ Cl,
    int Nc, int mode)
{
    __shared__ unsigned short sAh[64 * 136], sAl[64 * 136];   // [m][k]
    __shared__ unsigned short sWh[64 * 136], sWl[64 * 136];   // [n][k]
    int t = threadIdx.x;
    int row0 = blockIdx.y * 64, col0 = blockIdx.x * 64;

#pragma unroll
    for (int p = 0; p < 4; ++p) {
        int rr = (t >> 4) + p * 16, ck = t & 15;
        *(uint4*)&sWh[rr * 136 + ck * 8] = *(const uint4*)&WH[(long)(col0 + rr) * 128 + ck * 8];
        *(uint4*)&sWl[rr * 136 + ck * 8] = *(const uint4*)&WL[(long)(col0 + rr) * 128 + ck * 8];
    }
#pragma unroll
    for (int pass = 0; pass < 2; ++pass) {
        int row = pass * 32 + (t >> 3);
        int p = t & 7, cb = p * 16;
        float v[16];
        const float* xp = x + (long)(row0 + row) * HID + cb;
#pragma unroll
        for (int j = 0; j < 16; j += 4) *(float4*)&v[j] = *(const float4*)(xp + j);
        if (x2) {
            const float* yp = x2 + (long)(row0 + row) * HID + cb;
#pragma unroll
            for (int j = 0; j < 16; j += 4) {
                float4 r4 = *(const float4*)(yp + j);
                v[j] += r4.x; v[j+1] += r4.y; v[j+2] += r4.z; v[j+3] += r4.w;
            }
        }
        float s = 0.f, s2 = 0.f;
#pragma unroll
        for (int j = 0; j < 16; ++j) { s += v[j]; s2 += v[j] * v[j]; }
        s  += __shfl_xor(s, 1);  s  += __shfl_xor(s, 2);  s  += __shfl_xor(s, 4);
        s2 += __shfl_xor(s2, 1); s2 += __shfl_xor(s2, 2); s2 += __shfl_xor(s2, 4);
        float mu  = s * (1.f / HID);
        float var = s2 * (1.f / HID) - mu * mu;
        float inv = rsqrtf(var + 1e-5f);
        unsigned short hi[16], lo[16];
#pragma unroll
        for (int j = 0; j < 16; ++j) {
            int c = cb + j;
            float o = (v[j] - mu) * inv * g[c] + b[c];
            hi[j] = f2b(o); lo[j] = f2b(o - us2f(hi[j]));
        }
        *(uint4*)&sAh[row * 136 + cb]     = *(uint4*)&hi[0];
        *(uint4*)&sAh[row * 136 + cb + 8] = *(uint4*)&hi[8];
        *(uint4*)&sAl[row * 136 + cb]     = *(uint4*)&lo[0];
        *(uint4*)&sAl[row * 136 + cb + 8] = *(uint4*)&lo[8];
    }
    __syncthreads();

    int w = t >> 6, lane = t & 63;
    int m = lane & 15, quad = lane >> 4;
    f32x4 acc[4];
#pragma unroll
    for (int i = 0; i < 4; ++i) acc[i] = (f32x4){0.f, 0.f, 0.f, 0.f};
#pragma unroll
    for (int c = 0; c < 4; ++c) {
        bf16x8 ah = *(const bf16x8*)&sAh[(w * 16 + m) * 136 + c * 32 + quad * 8];
        bf16x8 al = *(const bf16x8*)&sAl[(w * 16 + m) * 136 + c * 32 + quad * 8];
#pragma unroll
        for (int nt = 0; nt < 4; ++nt) {
            bf16x8 wh = *(const bf16x8*)&sWh[(nt * 16 + m) * 136 + c * 32 + quad * 8];
            bf16x8 wl = *(const bf16x8*)&sWl[(nt * 16 + m) * 136 + c * 32 + quad * 8];
            acc[nt] = __builtin_amdgcn_mfma_f32_16x16x32_bf16(ah, wh, acc[nt], 0, 0, 0);
            acc[nt] = __builtin_amdgcn_mfma_f32_16x16x32_bf16(ah, wl, acc[nt], 0, 0, 0);
            acc[nt] = __builtin_amdgcn_mfma_f32_16x16x32_bf16(al, wh, acc[nt], 0, 0, 0);
        }
    }
#pragma unroll
    for (int nt = 0; nt < 4; ++nt) {
#pragma unroll
        for (int r = 0; r < 4; ++r) {
            int row = row0 + w * 16 + quad * 4 + r;
            int col = col0 + nt * 16 + m;
            float v = acc[nt][r];
            if (mode == 0) {
                Cf[(long)row * Nc + col] = v;
            } else {
                v = fmaxf(v, 0.f);
                unsigned short hh = f2b(v);
                Ch[(long)row * Nc + col] = hh;
                Cl[(long)row * Nc + col] = f2b(v - us2f(hh));
            }
        }
    }
}

// ---------- W2 GEMM + residual (+ fused decode on last layer): 16 rows x 128 cols/block.
__global__ __launch_bounds__(256, 3) void k_w2ln(
    const unsigned short* __restrict__ Ah, const unsigned short* __restrict__ Al,   // [4096][512]
    const unsigned short* __restrict__ WH, const unsigned short* __restrict__ WL,   // [128][512]
    const float* __restrict__ yres, float* __restrict__ hout,
    const float* __restrict__ Wdec, float* __restrict__ out)
{
    __shared__ unsigned short sA[2][16 * 72];
    __shared__ unsigned short sW[2][128 * 72];
    int t = threadIdx.x;
    int row0 = blockIdx.x * 16;
    int w = t >> 6, lane = t & 63;
    int m = lane & 15, quad = lane >> 4;
    f32x4 acc[2];
    acc[0] = (f32x4){0.f,0.f,0.f,0.f}; acc[1] = (f32x4){0.f,0.f,0.f,0.f};

    for (int ks = 0; ks < 512; ks += 64) {
        if (ks) __syncthreads();
        {
            int pl = t >> 7, tt = t & 127;
            int r = tt >> 3, ck = tt & 7;
            const unsigned short* src = pl ? Al : Ah;
            *(uint4*)&sA[pl][r * 72 + ck * 8] = *(const uint4*)&src[(long)(row0 + r) * 512 + ks + ck * 8];
        }
        {
            int r0 = t >> 3, ck = t & 7;
#pragma unroll
            for (int p = 0; p < 4; ++p) {
                int n = r0 + p * 32;
                *(uint4*)&sW[0][n * 72 + ck * 8] = *(const uint4*)&WH[(long)n * 512 + ks + ck * 8];
                *(uint4*)&sW[1][n * 72 + ck * 8] = *(const uint4*)&WL[(long)n * 512 + ks + ck * 8];
            }
        }
        __syncthreads();
#pragma unroll
        for (int c = 0; c < 2; ++c) {
            bf16x8 ah = *(const bf16x8*)&sA[0][m * 72 + c * 32 + quad * 8];
            bf16x8 al = *(const bf16x8*)&sA[1][m * 72 + c * 32 + quad * 8];
#pragma unroll
            for (int nt = 0; nt < 2; ++nt) {
                int n = w * 32 + nt * 16 + m;
                bf16x8 wh = *(const bf16x8*)&sW[0][n * 72 + c * 32 + quad * 8];
                bf16x8 wl = *(const bf16x8*)&sW[1][n * 72 + c * 32 + quad * 8];
                acc[nt] = __builtin_amdgcn_mfma_f32_16x16x32_bf16(ah, wh, acc[nt], 0, 0, 0);
                acc[nt] = __builtin_amdgcn_mfma_f32_16x16x32_bf16(ah, wl, acc[nt], 0, 0, 0);
                acc[nt] = __builtin_amdgcn_mfma_f32_16x16x32_bf16(al, wh, acc[nt], 0, 0, 0);
            }
        }
    }
    __syncthreads();                    // all sW reads done; reuse as fp32 tile
    float* ht = (float*)&sW[0][0];      // [16][132]
#pragma unroll
    for (int nt = 0; nt < 2; ++nt) {
#pragma unroll
        for (int r = 0; r < 4; ++r) {
            int row = quad * 4 + r;
            int col = w * 32 + nt * 16 + m;
            float v = acc[nt][r] + yres[(long)(row0 + row) * HID + col];
            hout[(long)(row0 + row) * HID + col] = v;
            ht[row * 132 + col] = v;
        }
    }
    __syncthreads();
    if (Wdec) {                         // fused decode: out = 10*tanh((h@Wdec)/sqrt(128))
        int row = t >> 4, sub = t & 15;
        float v[8];
        *(float4*)&v[0] = *(const float4*)&ht[row * 132 + sub * 8];
        *(float4*)&v[4] = *(const float4*)&ht[row * 132 + sub * 8 + 4];
        float a = 0.f;
#pragma unroll
        for (int j = 0; j < 8; ++j) a += v[j] * Wdec[sub * 8 + j];
        a += __shfl_xor(a, 1); a += __shfl_xor(a, 2); a += __shfl_xor(a, 4); a += __shfl_xor(a, 8);
        if (sub == 0) out[row0 + row] = 10.f * tanhf(a * 0.08838834764831845f);
    }
}

// ---------- attention: grid 512 = b x head x quarter; 4 waves x 16 q-rows.
// QK^T now split-bf16 MFMA (Q/K staged as hi/lo planes, k 16..31 zero via zeroed
// quad>=2 fragments); softmax (no max-sub) fp32 VALU; PV split-bf16 MFMA.
#define PAS 268   // u16 stride, 134 dwords === 6 mod 32 -> bank-floor frag reads/stores
#define KQS 20    // u16 stride for K/Q planes, 10 dwords -> bank-floor frag reads
__global__ __launch_bounds__(256) void k_attn(const float* __restrict__ qkv,
                                              const float* __restrict__ ef,
                                              const float* __restrict__ sbuf,
                                              int layer,
                                              float* __restrict__ y) {
    __shared__ unsigned short Kh[NS * KQS], Kl[NS * KQS];    // [key][d] 10.2 KB x2
    __shared__ unsigned short Qh[64 * KQS], Ql[64 * KQS];    // [qrow][d] 2.6 KB x2
    __shared__ unsigned short Vh[16 * PAS], Vl[16 * PAS];    // [d][key] 8.6 KB x2
    __shared__ unsigned short Pa[4][16 * PAS];               // per-wave [qrow][key] 34.3 KB
    int bid = blockIdx.x;
    int q4 = bid & 3, hh = (bid >> 2) & 7, bb = bid >> 5;
    int t = threadIdx.x;
    {   // stage K + V as bf16 hi/lo (one key row per thread)
        const float* kr = qkv + ((long)(bb * NS + t)) * 384 + HID + hh * 16;
        float kk[16];
        *(float4*)&kk[0]  = *(const float4*)kr;
        *(float4*)&kk[4]  = *(const float4*)(kr + 4);
        *(float4*)&kk[8]  = *(const float4*)(kr + 8);
        *(float4*)&kk[12] = *(const float4*)(kr + 12);
#pragma unroll
        for (int d = 0; d < 16; ++d) {
            unsigned short hi = f2b(kk[d]);
            Kh[t * KQS + d] = hi;
            Kl[t * KQS + d] = f2b(kk[d] - us2f(hi));
        }
        const float* vr = kr + HID;
        float vv[16];
        *(float4*)&vv[0]  = *(const float4*)vr;
        *(float4*)&vv[4]  = *(const float4*)(vr + 4);
        *(float4*)&vv[8]  = *(const float4*)(vr + 8);
        *(float4*)&vv[12] = *(const float4*)(vr + 12);
#pragma unroll
        for (int d = 0; d < 16; ++d) {
            unsigned short hi = f2b(vv[d]);
            Vh[d * PAS + t] = hi;
            Vl[d * PAS + t] = f2b(vv[d] - us2f(hi));
        }
    }
    {   // stage Q (this block's 64 q-rows): thread t -> row t>>2, 4-float chunk (t&3)
        int row = t >> 2, c4 = (t & 3) * 4;
        const float* qr = qkv + ((long)(bb * NS + q4 * 64 + row)) * 384 + hh * 16 + c4;
        float4 qv = *(const float4*)qr;
        float qq[4] = {qv.x, qv.y, qv.z, qv.w};
#pragma unroll
        for (int j = 0; j < 4; ++j) {
            unsigned short hi = f2b(qq[j]);
            Qh[row * KQS + c4 + j] = hi;
            Ql[row * KQS + c4 + j] = f2b(qq[j] - us2f(hi));
        }
    }
    __syncthreads();
    int w = t >> 6, lane = t & 63;
    int m = lane & 15, quad = lane >> 4;
    float s1  = sbuf[layer * 16 + hh];
    float s2g = sbuf[layer * 16 + NHEAD + hh];
    unsigned short* Paw = Pa[w];

    // Q A-fragment (once per wave): row = wave's q-row m, k = quad*8.. ; quads 2,3 = zero pad
    bf16x8 qh = (bf16x8){0,0,0,0,0,0,0,0}, ql = qh;
    if (quad < 2) {
        qh = *(const bf16x8*)&Qh[(w * 16 + m) * KQS + quad * 8];
        ql = *(const bf16x8*)&Ql[(w * 16 + m) * KQS + quad * 8];
    }
    // QK^T via MFMA: 16 col-tiles of 16 keys
    f32x4 sc[16];
#pragma unroll
    for (int ct = 0; ct < 16; ++ct) {
        bf16x8 kh = (bf16x8){0,0,0,0,0,0,0,0}, kl = kh;
        if (quad < 2) {
            kh = *(const bf16x8*)&Kh[(ct * 16 + m) * KQS + quad * 8];
            kl = *(const bf16x8*)&Kl[(ct * 16 + m) * KQS + quad * 8];
        }
        f32x4 a = (f32x4){0.f, 0.f, 0.f, 0.f};
        a = __builtin_amdgcn_mfma_f32_16x16x32_bf16(qh, kh, a, 0, 0, 0);
        a = __builtin_amdgcn_mfma_f32_16x16x32_bf16(qh, kl, a, 0, 0, 0);
        a = __builtin_amdgcn_mfma_f32_16x16x32_bf16(ql, kh, a, 0, 0, 0);
        sc[ct] = a;
    }
    // softmax (no max-sub: LN-bounded scores). C-layout: row = quad*4+r, col = ct*16+m.
    int baserow = q4 * 64 + w * 16 + quad * 4;
    float p[16][4], e[16][4];
#pragma unroll
    for (int ct = 0; ct < 16; ++ct) {
#pragma unroll
        for (int r = 0; r < 4; ++r) {
            e[ct][r] = ef[((long)(bb * NS + baserow + r)) * NS + ct * 16 + m];
            p[ct][r] = __expf(sc[ct][r] * 0.25f + e[ct][r] * s1);
        }
    }
    float inv[4];
#pragma unroll
    for (int r = 0; r < 4; ++r) {
        float s = 0.f;
#pragma unroll
        for (int ct = 0; ct < 16; ++ct) s += p[ct][r];
        s += __shfl_xor(s, 1); s += __shfl_xor(s, 2); s += __shfl_xor(s, 4); s += __shfl_xor(s, 8);
        inv[r] = s2g / s;
    }
#pragma unroll
    for (int ct = 0; ct < 16; ++ct) {
#pragma unroll
        for (int r = 0; r < 4; ++r) {
            Paw[(quad * 4 + r) * PAS + ct * 16 + m] = f2b(p[ct][r] * inv[r] * e[ct][r]);
        }
    }
    __syncthreads();   // guarantee all Pa writes visible before PV MFMA reads
    // PV via MFMA
    f32x4 acc = (f32x4){0.f, 0.f, 0.f, 0.f};
#pragma unroll
    for (int s = 0; s < 8; ++s) {
        bf16x8 pf = *(const bf16x8*)&Paw[m * PAS + s * 32 + quad * 8];
        bf16x8 vh = *(const bf16x8*)&Vh[m * PAS + s * 32 + quad * 8];
        bf16x8 vl = *(const bf16x8*)&Vl[m * PAS + s * 32 + quad * 8];
        acc = __builtin_amdgcn_mfma_f32_16x16x32_bf16(pf, vh, acc, 0, 0, 0);
        acc = __builtin_amdgcn_mfma_f32_16x16x32_bf16(pf, vl, acc, 0, 0, 0);
    }
#pragma unroll
    for (int r = 0; r < 4; ++r) {
        int row = q4 * 64 + w * 16 + quad * 4 + r;
        y[((long)(bb * NS + row)) * HID + hh * 16 + m] = acc[r];
    }
}

extern "C" void kernel_launch(void* const* d_in, const int* in_sizes, int n_in,
                              void* d_out, int out_size, void* d_ws, size_t ws_size,
                              hipStream_t stream) {
    const float* nf    = (const float*)d_in[0];
    const float* ef    = (const float*)d_in[1];
    const float* Wn    = (const float*)d_in[2];
    const float* We_in = (const float*)d_in[3];
    const float* ln1g  = (const float*)d_in[4];
    const float* ln1b  = (const float*)d_in[5];
    const float* Wh    = (const float*)d_in[6];
    const float* We    = (const float*)d_in[7];
    const float* ln2g  = (const float*)d_in[8];
    const float* ln2b  = (const float*)d_in[9];
    const float* W1    = (const float*)d_in[10];
    const float* W2    = (const float*)d_in[11];
    const float* Wdec  = (const float*)d_in[12];

    float* ws   = (float*)d_ws;
    float* sbuf = ws;                            // 64 slots
    float* h    = ws + 64;                       // 4096*128
    float* y    = h + ROWS * HID;                // 4096*128
    float* qkv  = y + ROWS * HID;                // 4096*384
    unsigned short* hidH = (unsigned short*)(qkv + (long)ROWS * 384);   // 4096*512
    unsigned short* hidL = hidH + (long)ROWS * 512;
    unsigned short* WhH  = hidL + (long)ROWS * 512;          // 3*384*128
    unsigned short* WhL  = WhH + (long)NL * 384 * 128;
    unsigned short* W1H  = WhL + (long)NL * 384 * 128;       // 3*512*128
    unsigned short* W1L  = W1H + (long)NL * 512 * 128;
    unsigned short* W2H  = W1L + (long)NL * 512 * 128;       // 3*128*512
    unsigned short* W2L  = W2H + (long)NL * 128 * 512;

    k_prep<<<529 + ROWS * HID / 256, 256, 0, stream>>>(Wh, W1, W2, We_in, We, nf, Wn,
                                    WhH, WhL, W1H, W1L, W2H, W2L, sbuf, h);
    for (int l = 0; l < NL; ++l) {
        // LN1 + QKV GEMM
        k_fgemm<<<dim3(6, 64), 256, 0, stream>>>(h, nullptr,
            ln1g + l * HID, ln1b + l * HID,
            WhH + (long)l * 384 * 128, WhL + (long)l * 384 * 128,
            qkv, nullptr, nullptr, 384, 0);
        k_attn<<<512, 256, 0, stream>>>(qkv, ef, sbuf, l, y);
        // LN2(y+h) + W1 GEMM + relu -> planes
        k_fgemm<<<dim3(8, 64), 256, 0, stream>>>(y, h,
            ln2g + l * HID, ln2b + l * HID,
            W1H + (long)l * 512 * 128, W1L + (long)l * 512 * 128,
            nullptr, hidH, hidL, 512, 1);
        // W2 GEMM + residual -> h (+ decode on last layer)
        int last = (l == NL - 1);
        k_w2ln<<<ROWS / 16, 256, 0, stream>>>(hidH, hidL,
            W2H + (long)l * 128 * 512, W2L + (long)l * 128 * 512,
            y, h, last ? Wdec : nullptr, (float*)d_out);
    }
}

// Round 15
// 216.470 us; speedup vs baseline: 1.1569x; 1.0078x over previous
//
#include <hip/hip_runtime.h>
#include <math.h>

#define HID 128
#define NHEAD 8
#define NL 3
#define NS 256
#define ROWS 4096

typedef __attribute__((ext_vector_type(8))) short bf16x8;
typedef __attribute__((ext_vector_type(4))) float f32x4;

__device__ __forceinline__ float us2f(unsigned short s) { return __uint_as_float(((unsigned)s) << 16); }
__device__ __forceinline__ unsigned short f2b(float f) {   // RNE fp32->bf16
    unsigned u = __float_as_uint(f);
    return (unsigned short)((u + 0x7fff + ((u >> 16) & 1)) >> 16);
}

// ---------- prep: weight split+transpose to bf16 hi/lo planes [N][K] + edge scalars + embed
// blocks: [0,144) Wh, [144,336) W1, [336,528) W2, 528 edge scalars, [529,2577) embed h=nf@Wn
__global__ __launch_bounds__(256) void k_prep(
    const float* __restrict__ Wh, const float* __restrict__ W1, const float* __restrict__ W2,
    const float* __restrict__ We_in, const float* __restrict__ We,
    const float* __restrict__ nf, const float* __restrict__ Wn,
    unsigned short* __restrict__ WhH, unsigned short* __restrict__ WhL,
    unsigned short* __restrict__ W1H, unsigned short* __restrict__ W1L,
    unsigned short* __restrict__ W2H, unsigned short* __restrict__ W2L,
    float* __restrict__ sbuf, float* __restrict__ h)
{
    int b = blockIdx.x, t = threadIdx.x;
    if (b >= 529) {                       // embed
        int idx = (b - 529) * 256 + t;
        int r = idx >> 7, c = idx & 127;
        h[idx] = nf[2 * r] * Wn[c] + nf[2 * r + 1] * Wn[HID + c];
        return;
    }
    if (b == 528) {                       // edge scalars (rank-1 collapse of e @ We)
        if (t < NL * 2 * NHEAD) {
            int l = t / (2 * NHEAD), j = t % (2 * NHEAD);
            float acc = 0.f;
            for (int c = 0; c < HID; ++c)
                acc += We_in[c] * We[(long)(l * HID + c) * (2 * NHEAD) + j];
            sbuf[t] = acc;
        }
        return;
    }
    const float* S; unsigned short *OH, *OL; int K, N, kt, nt;
    if (b < 144) {
        int l = b / 48, rem = b % 48; kt = rem & 3; nt = rem >> 2; K = 128; N = 384;
        S = Wh + (long)l * 128 * 384; OH = WhH + (long)l * 384 * 128; OL = WhL + (long)l * 384 * 128;
    } else if (b < 336) {
        int b2 = b - 144; int l = b2 / 64, rem = b2 % 64; kt = rem & 3; nt = rem >> 2; K = 128; N = 512;
        S = W1 + (long)l * 128 * 512; OH = W1H + (long)l * 512 * 128; OL = W1L + (long)l * 512 * 128;
    } else {
        int b2 = b - 336; int l = b2 / 64, rem = b2 % 64; kt = rem & 15; nt = rem >> 4; K = 512; N = 128;
        S = W2 + (long)l * 512 * 128; OH = W2H + (long)l * 128 * 512; OL = W2L + (long)l * 128 * 512;
    }
    __shared__ float sm[32][33];
    int i0 = t >> 5, j = t & 31;
#pragma unroll
    for (int p = 0; p < 4; ++p) {
        int i = i0 + p * 8;
        sm[i][j] = S[(long)(kt * 32 + i) * N + nt * 32 + j];
    }
    __syncthreads();
#pragma unroll
    for (int p = 0; p < 4; ++p) {
        int n = i0 + p * 8;
        float v = sm[j][n];
        unsigned short hh = f2b(v);
        long o = (long)(nt * 32 + n) * K + kt * 32 + j;
        OH[o] = hh; OL[o] = f2b(v - us2f(hh));
    }
}

// ---------- fused LN + split-bf16 MFMA GEMM, K=128 single-shot, 64x64 tile, 4 waves.
// epilogue always emits split hi/lo planes; mode 1 applies relu first.
__global__ __launch_bounds__(256) void k_fgemm(
    const float* __restrict__ x, const float* __restrict__ x2,
    const float* __restrict__ g, const float* __restrict__ b,
    const unsigned short* __restrict__ WH, const unsigned short* __restrict__ WL,
    unsigned short* __restrict__ Ch, unsigned short* __restrict__ Cl,
    int Nc, int mode)
{
    __shared__ unsigned short sAh[64 * 136], sAl[64 * 136];   // [m][k]
    __shared__ unsigned short sWh[64 * 136], sWl[64 * 136];   // [n][k]
    int t = threadIdx.x;
    int row0 = blockIdx.y * 64, col0 = blockIdx.x * 64;

#pragma unroll
    for (int p = 0; p < 4; ++p) {
        int rr = (t >> 4) + p * 16, ck = t & 15;
        *(uint4*)&sWh[rr * 136 + ck * 8] = *(const uint4*)&WH[(long)(col0 + rr) * 128 + ck * 8];
        *(uint4*)&sWl[rr * 136 + ck * 8] = *(const uint4*)&WL[(long)(col0 + rr) * 128 + ck * 8];
    }
#pragma unroll
    for (int pass = 0; pass < 2; ++pass) {
        int row = pass * 32 + (t >> 3);
        int p = t & 7, cb = p * 16;
        float v[16];
        const float* xp = x + (long)(row0 + row) * HID + cb;
#pragma unroll
        for (int j = 0; j < 16; j += 4) *(float4*)&v[j] = *(const float4*)(xp + j);
        if (x2) {
            const float* yp = x2 + (long)(row0 + row) * HID + cb;
#pragma unroll
            for (int j = 0; j < 16; j += 4) {
                float4 r4 = *(const float4*)(yp + j);
                v[j] += r4.x; v[j+1] += r4.y; v[j+2] += r4.z; v[j+3] += r4.w;
            }
        }
        float s = 0.f, s2 = 0.f;
#pragma unroll
        for (int j = 0; j < 16; ++j) { s += v[j]; s2 += v[j] * v[j]; }
        s  += __shfl_xor(s, 1);  s  += __shfl_xor(s, 2);  s  += __shfl_xor(s, 4);
        s2 += __shfl_xor(s2, 1); s2 += __shfl_xor(s2, 2); s2 += __shfl_xor(s2, 4);
        float mu  = s * (1.f / HID);
        float var = s2 * (1.f / HID) - mu * mu;
        float inv = rsqrtf(var + 1e-5f);
        unsigned short hi[16], lo[16];
#pragma unroll
        for (int j = 0; j < 16; ++j) {
            int c = cb + j;
            float o = (v[j] - mu) * inv * g[c] + b[c];
            hi[j] = f2b(o); lo[j] = f2b(o - us2f(hi[j]));
        }
        *(uint4*)&sAh[row * 136 + cb]     = *(uint4*)&hi[0];
        *(uint4*)&sAh[row * 136 + cb + 8] = *(uint4*)&hi[8];
        *(uint4*)&sAl[row * 136 + cb]     = *(uint4*)&lo[0];
        *(uint4*)&sAl[row * 136 + cb + 8] = *(uint4*)&lo[8];
    }
    __syncthreads();

    int w = t >> 6, lane = t & 63;
    int m = lane & 15, quad = lane >> 4;
    f32x4 acc[4];
#pragma unroll
    for (int i = 0; i < 4; ++i) acc[i] = (f32x4){0.f, 0.f, 0.f, 0.f};
#pragma unroll
    for (int c = 0; c < 4; ++c) {
        bf16x8 ah = *(const bf16x8*)&sAh[(w * 16 + m) * 136 + c * 32 + quad * 8];
        bf16x8 al = *(const bf16x8*)&sAl[(w * 16 + m) * 136 + c * 32 + quad * 8];
#pragma unroll
        for (int nt = 0; nt < 4; ++nt) {
            bf16x8 wh = *(const bf16x8*)&sWh[(nt * 16 + m) * 136 + c * 32 + quad * 8];
            bf16x8 wl = *(const bf16x8*)&sWl[(nt * 16 + m) * 136 + c * 32 + quad * 8];
            acc[nt] = __builtin_amdgcn_mfma_f32_16x16x32_bf16(ah, wh, acc[nt], 0, 0, 0);
            acc[nt] = __builtin_amdgcn_mfma_f32_16x16x32_bf16(ah, wl, acc[nt], 0, 0, 0);
            acc[nt] = __builtin_amdgcn_mfma_f32_16x16x32_bf16(al, wh, acc[nt], 0, 0, 0);
        }
    }
#pragma unroll
    for (int nt = 0; nt < 4; ++nt) {
#pragma unroll
        for (int r = 0; r < 4; ++r) {
            int row = row0 + w * 16 + quad * 4 + r;
            int col = col0 + nt * 16 + m;
            float v = acc[nt][r];
            if (mode) v = fmaxf(v, 0.f);
            unsigned short hh = f2b(v);
            Ch[(long)row * Nc + col] = hh;
            Cl[(long)row * Nc + col] = f2b(v - us2f(hh));
        }
    }
}

// ---------- W2 GEMM + residual (+ fused decode on last layer): 16 rows x 128 cols/block.
__global__ __launch_bounds__(256, 3) void k_w2ln(
    const unsigned short* __restrict__ Ah, const unsigned short* __restrict__ Al,   // [4096][512]
    const unsigned short* __restrict__ WH, const unsigned short* __restrict__ WL,   // [128][512]
    const float* __restrict__ yres, float* __restrict__ hout,
    const float* __restrict__ Wdec, float* __restrict__ out)
{
    __shared__ unsigned short sA[2][16 * 72];
    __shared__ unsigned short sW[2][128 * 72];
    int t = threadIdx.x;
    int row0 = blockIdx.x * 16;
    int w = t >> 6, lane = t & 63;
    int m = lane & 15, quad = lane >> 4;
    f32x4 acc[2];
    acc[0] = (f32x4){0.f,0.f,0.f,0.f}; acc[1] = (f32x4){0.f,0.f,0.f,0.f};

    for (int ks = 0; ks < 512; ks += 64) {
        if (ks) __syncthreads();
        {
            int pl = t >> 7, tt = t & 127;
            int r = tt >> 3, ck = tt & 7;
            const unsigned short* src = pl ? Al : Ah;
            *(uint4*)&sA[pl][r * 72 + ck * 8] = *(const uint4*)&src[(long)(row0 + r) * 512 + ks + ck * 8];
        }
        {
            int r0 = t >> 3, ck = t & 7;
#pragma unroll
            for (int p = 0; p < 4; ++p) {
                int n = r0 + p * 32;
                *(uint4*)&sW[0][n * 72 + ck * 8] = *(const uint4*)&WH[(long)n * 512 + ks + ck * 8];
                *(uint4*)&sW[1][n * 72 + ck * 8] = *(const uint4*)&WL[(long)n * 512 + ks + ck * 8];
            }
        }
        __syncthreads();
#pragma unroll
        for (int c = 0; c < 2; ++c) {
            bf16x8 ah = *(const bf16x8*)&sA[0][m * 72 + c * 32 + quad * 8];
            bf16x8 al = *(const bf16x8*)&sA[1][m * 72 + c * 32 + quad * 8];
#pragma unroll
            for (int nt = 0; nt < 2; ++nt) {
                int n = w * 32 + nt * 16 + m;
                bf16x8 wh = *(const bf16x8*)&sW[0][n * 72 + c * 32 + quad * 8];
                bf16x8 wl = *(const bf16x8*)&sW[1][n * 72 + c * 32 + quad * 8];
                acc[nt] = __builtin_amdgcn_mfma_f32_16x16x32_bf16(ah, wh, acc[nt], 0, 0, 0);
                acc[nt] = __builtin_amdgcn_mfma_f32_16x16x32_bf16(ah, wl, acc[nt], 0, 0, 0);
                acc[nt] = __builtin_amdgcn_mfma_f32_16x16x32_bf16(al, wh, acc[nt], 0, 0, 0);
            }
        }
    }
    __syncthreads();                    // all sW reads done; reuse as fp32 tile
    float* ht = (float*)&sW[0][0];      // [16][132]
#pragma unroll
    for (int nt = 0; nt < 2; ++nt) {
#pragma unroll
        for (int r = 0; r < 4; ++r) {
            int row = quad * 4 + r;
            int col = w * 32 + nt * 16 + m;
            float v = acc[nt][r] + yres[(long)(row0 + row) * HID + col];
            hout[(long)(row0 + row) * HID + col] = v;
            ht[row * 132 + col] = v;
        }
    }
    __syncthreads();
    if (Wdec) {                         // fused decode: out = 10*tanh((h@Wdec)/sqrt(128))
        int row = t >> 4, sub = t & 15;
        float v[8];
        *(float4*)&v[0] = *(const float4*)&ht[row * 132 + sub * 8];
        *(float4*)&v[4] = *(const float4*)&ht[row * 132 + sub * 8 + 4];
        float a = 0.f;
#pragma unroll
        for (int j = 0; j < 8; ++j) a += v[j] * Wdec[sub * 8 + j];
        a += __shfl_xor(a, 1); a += __shfl_xor(a, 2); a += __shfl_xor(a, 4); a += __shfl_xor(a, 8);
        if (sub == 0) out[row0 + row] = 10.f * tanhf(a * 0.08838834764831845f);
    }
}

// ---------- attention: grid 512 = b x head x quarter; 4 waves x 16 q-rows.
// qkv arrives pre-split (hi/lo u16 planes) -> staging is pure copies.
// QK^T split-bf16 MFMA; softmax (no max-sub) with DEFERRED normalization:
// Pa = p*e (bf16), acc scaled by s2g/sum after PV. PV split-bf16 MFMA.
#define PAS 268   // u16 stride, 134 dwords === 6 mod 32 -> bank-floor frag reads/stores
#define KQS 20    // u16 stride for K/Q planes, 10 dwords -> bank-floor frag reads
__global__ __launch_bounds__(256) void k_attn(
    const unsigned short* __restrict__ qkvH, const unsigned short* __restrict__ qkvL,
    const float* __restrict__ ef, const float* __restrict__ sbuf,
    int layer, float* __restrict__ y)
{
    __shared__ unsigned short Kh[NS * KQS], Kl[NS * KQS];    // [key][d]
    __shared__ unsigned short Qh[64 * KQS], Ql[64 * KQS];    // [qrow][d]
    __shared__ unsigned short Vh[16 * PAS], Vl[16 * PAS];    // [d][key]
    __shared__ unsigned short Pa[4][16 * PAS];               // per-wave [qrow][key]
    int bid = blockIdx.x;
    int q4 = bid & 3, hh = (bid >> 2) & 7, bb = bid >> 5;
    int t = threadIdx.x;
    {   // stage K + V (pre-split planes; one key row per thread)
        long kb = ((long)(bb * NS + t)) * 384 + HID + hh * 16;
        union { uint4 u[2]; unsigned short s[16]; } KH, KL, VH, VL;
        KH.u[0] = *(const uint4*)&qkvH[kb];       KH.u[1] = *(const uint4*)&qkvH[kb + 8];
        KL.u[0] = *(const uint4*)&qkvL[kb];       KL.u[1] = *(const uint4*)&qkvL[kb + 8];
        VH.u[0] = *(const uint4*)&qkvH[kb + 128]; VH.u[1] = *(const uint4*)&qkvH[kb + 136];
        VL.u[0] = *(const uint4*)&qkvL[kb + 128]; VL.u[1] = *(const uint4*)&qkvL[kb + 136];
#pragma unroll
        for (int d = 0; d < 16; ++d) {
            Kh[t * KQS + d] = KH.s[d];
            Kl[t * KQS + d] = KL.s[d];
            Vh[d * PAS + t] = VH.s[d];
            Vl[d * PAS + t] = VL.s[d];
        }
    }
    {   // stage Q: thread t -> row t>>2, 4-elem chunk (t&3)*4
        int row = t >> 2, c4 = (t & 3) * 4;
        long qb = ((long)(bb * NS + q4 * 64 + row)) * 384 + hh * 16 + c4;
        union { uint2 u; unsigned short s[4]; } QH, QL;
        QH.u = *(const uint2*)&qkvH[qb];
        QL.u = *(const uint2*)&qkvL[qb];
#pragma unroll
        for (int j = 0; j < 4; ++j) {
            Qh[row * KQS + c4 + j] = QH.s[j];
            Ql[row * KQS + c4 + j] = QL.s[j];
        }
    }
    __syncthreads();
    int w = t >> 6, lane = t & 63;
    int m = lane & 15, quad = lane >> 4;
    float s1  = sbuf[layer * 16 + hh];
    float s2g = sbuf[layer * 16 + NHEAD + hh];
    unsigned short* Paw = Pa[w];

    // Q A-fragment (once per wave): quads 2,3 = zero pad (k 16..31)
    bf16x8 qh = (bf16x8){0,0,0,0,0,0,0,0}, ql = qh;
    if (quad < 2) {
        qh = *(const bf16x8*)&Qh[(w * 16 + m) * KQS + quad * 8];
        ql = *(const bf16x8*)&Ql[(w * 16 + m) * KQS + quad * 8];
    }
    // QK^T via MFMA: 16 col-tiles of 16 keys
    f32x4 sc[16];
#pragma unroll
    for (int ct = 0; ct < 16; ++ct) {
        bf16x8 kh = (bf16x8){0,0,0,0,0,0,0,0}, kl = kh;
        if (quad < 2) {
            kh = *(const bf16x8*)&Kh[(ct * 16 + m) * KQS + quad * 8];
            kl = *(const bf16x8*)&Kl[(ct * 16 + m) * KQS + quad * 8];
        }
        f32x4 a = (f32x4){0.f, 0.f, 0.f, 0.f};
        a = __builtin_amdgcn_mfma_f32_16x16x32_bf16(qh, kh, a, 0, 0, 0);
        a = __builtin_amdgcn_mfma_f32_16x16x32_bf16(qh, kl, a, 0, 0, 0);
        a = __builtin_amdgcn_mfma_f32_16x16x32_bf16(ql, kh, a, 0, 0, 0);
        sc[ct] = a;
    }
    // softmax, deferred normalization: Pa = p*e, running row-sums only.
    int baserow = q4 * 64 + w * 16 + quad * 4;
    float s[4] = {0.f, 0.f, 0.f, 0.f};
#pragma unroll
    for (int ct = 0; ct < 16; ++ct) {
#pragma unroll
        for (int r = 0; r < 4; ++r) {
            float e = ef[((long)(bb * NS + baserow + r)) * NS + ct * 16 + m];
            float p = __expf(sc[ct][r] * 0.25f + e * s1);
            s[r] += p;
            Paw[(quad * 4 + r) * PAS + ct * 16 + m] = f2b(p * e);
        }
    }
    float inv[4];
#pragma unroll
    for (int r = 0; r < 4; ++r) {
        float ss = s[r];
        ss += __shfl_xor(ss, 1); ss += __shfl_xor(ss, 2);
        ss += __shfl_xor(ss, 4); ss += __shfl_xor(ss, 8);
        inv[r] = s2g / ss;
    }
    __syncthreads();   // guarantee all Pa writes visible before PV MFMA reads
    // PV via MFMA, then per-row normalization
    f32x4 acc = (f32x4){0.f, 0.f, 0.f, 0.f};
#pragma unroll
    for (int sft = 0; sft < 8; ++sft) {
        bf16x8 pf = *(const bf16x8*)&Paw[m * PAS + sft * 32 + quad * 8];
        bf16x8 vh = *(const bf16x8*)&Vh[m * PAS + sft * 32 + quad * 8];
        bf16x8 vl = *(const bf16x8*)&Vl[m * PAS + sft * 32 + quad * 8];
        acc = __builtin_amdgcn_mfma_f32_16x16x32_bf16(pf, vh, acc, 0, 0, 0);
        acc = __builtin_amdgcn_mfma_f32_16x16x32_bf16(pf, vl, acc, 0, 0, 0);
    }
#pragma unroll
    for (int r = 0; r < 4; ++r) {
        int row = q4 * 64 + w * 16 + quad * 4 + r;
        y[((long)(bb * NS + row)) * HID + hh * 16 + m] = acc[r] * inv[r];
    }
}

extern "C" void kernel_launch(void* const* d_in, const int* in_sizes, int n_in,
                              void* d_out, int out_size, void* d_ws, size_t ws_size,
                              hipStream_t stream) {
    const float* nf    = (const float*)d_in[0];
    const float* ef    = (const float*)d_in[1];
    const float* Wn    = (const float*)d_in[2];
    const float* We_in = (const float*)d_in[3];
    const float* ln1g  = (const float*)d_in[4];
    const float* ln1b  = (const float*)d_in[5];
    const float* Wh    = (const float*)d_in[6];
    const float* We    = (const float*)d_in[7];
    const float* ln2g  = (const float*)d_in[8];
    const float* ln2b  = (const float*)d_in[9];
    const float* W1    = (const float*)d_in[10];
    const float* W2    = (const float*)d_in[11];
    const float* Wdec  = (const float*)d_in[12];

    float* ws   = (float*)d_ws;
    float* sbuf = ws;                            // 64 slots
    float* h    = ws + 64;                       // 4096*128
    float* y    = h + ROWS * HID;                // 4096*128
    unsigned short* qkvH = (unsigned short*)(y + ROWS * HID);   // 4096*384 u16
    unsigned short* qkvL = qkvH + (long)ROWS * 384;
    unsigned short* hidH = qkvL + (long)ROWS * 384;             // 4096*512
    unsigned short* hidL = hidH + (long)ROWS * 512;
    unsigned short* WhH  = hidL + (long)ROWS * 512;             // 3*384*128
    unsigned short* WhL  = WhH + (long)NL * 384 * 128;
    unsigned short* W1H  = WhL + (long)NL * 384 * 128;          // 3*512*128
    unsigned short* W1L  = W1H + (long)NL * 512 * 128;
    unsigned short* W2H  = W1L + (long)NL * 512 * 128;          // 3*128*512
    unsigned short* W2L  = W2H + (long)NL * 128 * 512;

    k_prep<<<529 + ROWS * HID / 256, 256, 0, stream>>>(Wh, W1, W2, We_in, We, nf, Wn,
                                    WhH, WhL, W1H, W1L, W2H, W2L, sbuf, h);
    for (int l = 0; l < NL; ++l) {
        // LN1 + QKV GEMM -> split planes
        k_fgemm<<<dim3(6, 64), 256, 0, stream>>>(h, nullptr,
            ln1g + l * HID, ln1b + l * HID,
            WhH + (long)l * 384 * 128, WhL + (long)l * 384 * 128,
            qkvH, qkvL, 384, 0);
        k_attn<<<512, 256, 0, stream>>>(qkvH, qkvL, ef, sbuf, l, y);
        // LN2(y+h) + W1 GEMM + relu -> planes
        k_fgemm<<<dim3(8, 64), 256, 0, stream>>>(y, h,
            ln2g + l * HID, ln2b + l * HID,
            W1H + (long)l * 512 * 128, W1L + (long)l * 512 * 128,
            hidH, hidL, 512, 1);
        // W2 GEMM + residual -> h (+ decode on last layer)
        int last = (l == NL - 1);
        k_w2ln<<<ROWS / 16, 256, 0, stream>>>(hidH, hidL,
            W2H + (long)l * 128 * 512, W2L + (long)l * 128 * 512,
            y, h, last ? Wdec : nullptr, (float*)d_out);
    }
}